// Round 1
// baseline (822.539 us; speedup 1.0000x reference)
//
#include <hip/hip_runtime.h>

// Problem constants
constexpr int N = 16, C = 64, H = 128, W = 128, P = H * W;   // P = 16384
constexpr int NL = 256, PK = 1024;                            // 256 windows, 32x32 each

// Workspace layout (floats)
constexpr size_t OFF_X1    = 0;                // 16,777,216  (later reused as pr)
constexpr size_t OFF_X2    = 16777216;         // 16,777,216
constexpr size_t OFF_POOL  = 33554432;         // 16,777,216  (later reused as assembled out)
constexpr size_t OFF_SUMS  = 50331648;         // 16,384
constexpr size_t OFF_SCALE = OFF_SUMS + 16384; // 16,384
constexpr size_t OFF_WMOD  = OFF_SCALE + 16384;// 36,864  (merged+transposed 3x3 weights)

// ---------------------------------------------------------------------------
// K0: merge conv2 (1x1) into center tap of pos_w, transpose to [ci][tap][co];
//     also zero the SE sums buffer (ws is poisoned 0xAA before every launch).
__global__ __launch_bounds__(256) void k0_prep(const float* __restrict__ pos_w,
                                               const float* __restrict__ conv2_w,
                                               float* __restrict__ wmod,
                                               float* __restrict__ sums) {
    int t = blockIdx.x * 256 + threadIdx.x;
    if (t < 64 * 9 * 64) {
        int co  = t & 63;
        int tap = (t >> 6) % 9;
        int ci  = (t >> 6) / 9;
        float v = pos_w[(co * 64 + ci) * 9 + tap];
        if (tap == 4) v += conv2_w[co * 64 + ci];
        wmod[t] = v;                       // t == ci*576 + tap*64 + co
    } else {
        int u = t - 64 * 9 * 64;
        if (u < 16384) sums[u] = 0.f;
    }
}

// ---------------------------------------------------------------------------
// K1: conv1 (1x1, 64 -> 128 ch) + bias. GEMM tile: 128 co x 64 px, K=64.
// x tile staged in LDS; weights via L1-cached global float4 loads.
__global__ __launch_bounds__(256) void k1_conv1(const float* __restrict__ x,
                                                const float* __restrict__ w1,
                                                const float* __restrict__ b1,
                                                float* __restrict__ x1,
                                                float* __restrict__ x2) {
    __shared__ __align__(16) float lx[64 * 64];
    int bid = blockIdx.x;
    int n   = bid >> 8;
    int p0  = (bid & 255) << 6;
    const float* xg = x + (size_t)n * C * P + p0;
    int t = threadIdx.x;
    // stage 64ci x 64px tile
    #pragma unroll
    for (int k = 0; k < 4; ++k) {
        int u = t + k * 256;               // float4 units, 1024 total
        int ci = u >> 4, px4 = u & 15;
        *(float4*)(lx + ci * 64 + px4 * 4) = *(const float4*)(xg + ci * P + px4 * 4);
    }
    __syncthreads();
    int cog = t & 31, pxg = t >> 5;        // 32 co-groups x 8 px-groups
    int co0 = cog * 4, px0 = pxg * 8;
    float acc[4][8];
    #pragma unroll
    for (int c = 0; c < 4; ++c) {
        float b = b1[co0 + c];
        #pragma unroll
        for (int p = 0; p < 8; ++p) acc[c][p] = b;
    }
    for (int cb = 0; cb < 16; ++cb) {      // K blocks of 4
        float4 w4[4];
        #pragma unroll
        for (int c = 0; c < 4; ++c)
            w4[c] = *(const float4*)(w1 + (co0 + c) * 64 + cb * 4);
        float4 xv[4][2];
        #pragma unroll
        for (int q = 0; q < 4; ++q) {
            xv[q][0] = *(const float4*)(lx + (cb * 4 + q) * 64 + px0);
            xv[q][1] = *(const float4*)(lx + (cb * 4 + q) * 64 + px0 + 4);
        }
        #pragma unroll
        for (int q = 0; q < 4; ++q) {
            const float* xa = (const float*)&xv[q][0];
            const float* xb = (const float*)&xv[q][1];
            #pragma unroll
            for (int c = 0; c < 4; ++c) {
                float wv = ((const float*)&w4[c])[q];
                #pragma unroll
                for (int p = 0; p < 4; ++p) {
                    acc[c][p]     += wv * xa[p];
                    acc[c][p + 4] += wv * xb[p];
                }
            }
        }
    }
    #pragma unroll
    for (int c = 0; c < 4; ++c) {
        int co = co0 + c;
        float* dst = (co < 64) ? (x1 + ((size_t)n * 64 + co) * P + p0 + px0)
                               : (x2 + ((size_t)n * 64 + (co - 64)) * P + p0 + px0);
        *(float4*)dst       = make_float4(acc[c][0], acc[c][1], acc[c][2], acc[c][3]);
        *(float4*)(dst + 4) = make_float4(acc[c][4], acc[c][5], acc[c][6], acc[c][7]);
    }
}

// ---------------------------------------------------------------------------
// K2: edge-pad + window partition + adaptive pool 34->32 == 2x2 avg with
// clamped indices: s(o) = o + (o>=16), inputs {s, s+1}, weight 1/4.
__global__ __launch_bounds__(256) void k2_pool(const float* __restrict__ x1,
                                               float* __restrict__ pooled) {
    int tid = blockIdx.x * 256 + threadIdx.x;  // 16,777,216 = 256nl * 64c * 1024px
    int ow = tid & 31;
    int oh = (tid >> 5) & 31;
    int c  = (tid >> 10) & 63;
    int nl = tid >> 16;
    int n = nl >> 4, l = nl & 15;
    int i = l >> 2, j = l & 3;
    int sh = oh + (oh >> 4);
    int sw = ow + (ow >> 4);
    int u = i * 34 + sh - 4;
    int v = j * 34 + sw - 4;
    int r0 = min(max(u, 0), 127), r1 = min(max(u + 1, 0), 127);
    int c0 = min(max(v, 0), 127), c1 = min(max(v + 1, 0), 127);
    const float* src = x1 + ((size_t)n * 64 + c) * P;
    pooled[tid] = 0.25f * (src[r0 * 128 + c0] + src[r0 * 128 + c1] +
                           src[r1 * 128 + c0] + src[r1 * 128 + c1]);
}

// ---------------------------------------------------------------------------
// K3: pr = 3x3 SAME conv (with conv2 folded into center tap) + biases.
// Block: one nl, 2 rows x 32 cols x all 64 co. K-loop over 4 chunks of 16 ci.
// Also produces per-(nl,co) sums for the SE mean (block reduce + 1 atomic/co).
__global__ __launch_bounds__(256) void k3_pr(const float* __restrict__ pooled,
                                             const float* __restrict__ wmod,
                                             const float* __restrict__ b2,
                                             const float* __restrict__ posb,
                                             float* __restrict__ pr,
                                             float* __restrict__ sums) {
    __shared__ __align__(16) float lw[16 * 9 * 64];   // [ci][tap][co]  36 KB
    __shared__ __align__(16) float lxs[16 * 4 * 35];  // [ci][4 rows][35 cols] ~9 KB
    __shared__ float red[16 * 64];                    // 4 KB
    int bid  = blockIdx.x;
    int nl   = bid >> 4;
    int row0 = (bid & 15) * 2;
    int t    = threadIdx.x;
    int cog = t & 15, pxg = t >> 4;
    int co0 = cog * 4;
    int prow  = row0 + (pxg >> 3);
    int pcol0 = (pxg & 7) * 4;
    float acc[4][4] = {};
    const float* psrc = pooled + (size_t)nl * 64 * PK;
    for (int cb = 0; cb < 4; ++cb) {
        __syncthreads();
        {   // stage weights chunk (contiguous: coalesced read, linear LDS write)
            const float* wsrc = wmod + cb * 9216;
            #pragma unroll
            for (int k = 0; k < 36; ++k) lw[t + k * 256] = wsrc[t + k * 256];
        }
        {   // stage input chunk with 1-px zero halo: rows row0-1..row0+2, cols -1..32
            for (int k = 0; k < 9; ++k) {
                int e = t + k * 256;
                if (e < 16 * 136) {
                    int ci_l = e / 136;
                    int rem  = e - ci_l * 136;
                    int r    = rem / 34;
                    int col  = rem - r * 34;
                    int srow = row0 - 1 + r;
                    int scol = col - 1;
                    float vv = 0.f;
                    if (srow >= 0 && srow < 32 && scol >= 0 && scol < 32)
                        vv = psrc[(cb * 16 + ci_l) * PK + srow * 32 + scol];
                    lxs[ci_l * 140 + r * 35 + col] = vv;
                }
            }
        }
        __syncthreads();
        for (int ci = 0; ci < 16; ++ci) {
            #pragma unroll
            for (int kh = 0; kh < 3; ++kh) {
                int lr = (pxg >> 3) + kh;
                const float* xrow = lxs + ci * 140 + lr * 35 + pcol0;
                float xw[6];
                #pragma unroll
                for (int q = 0; q < 6; ++q) xw[q] = xrow[q];
                #pragma unroll
                for (int kw = 0; kw < 3; ++kw) {
                    float4 w4 = *(const float4*)(lw + ci * 576 + (kh * 3 + kw) * 64 + co0);
                    const float* wp = (const float*)&w4;
                    #pragma unroll
                    for (int c = 0; c < 4; ++c)
                        #pragma unroll
                        for (int p = 0; p < 4; ++p)
                            acc[c][p] += wp[c] * xw[kw + p];
                }
            }
        }
    }
    float psum[4];
    #pragma unroll
    for (int c = 0; c < 4; ++c) {
        int co = co0 + c;
        float bias = b2[co] + posb[co];
        float4 o;
        float* op = (float*)&o;
        float s = 0.f;
        #pragma unroll
        for (int p = 0; p < 4; ++p) { op[p] = acc[c][p] + bias; s += op[p]; }
        psum[c] = s;
        *(float4*)(pr + (size_t)nl * 65536 + co * PK + prow * 32 + pcol0) = o;
    }
    #pragma unroll
    for (int c = 0; c < 4; ++c) red[pxg * 64 + co0 + c] = psum[c];
    __syncthreads();
    if (t < 64) {
        float s = 0.f;
        #pragma unroll
        for (int pg = 0; pg < 16; ++pg) s += red[pg * 64 + t];
        atomicAdd(&sums[nl * 64 + t], s);
    }
}

// ---------------------------------------------------------------------------
// K3b: SE block per nl: mean -> 64->8 relu -> 8->64 sigmoid; scale = 1 + s.
__global__ __launch_bounds__(64) void k3b_se(const float* __restrict__ sums,
                                             const float* __restrict__ w1,
                                             const float* __restrict__ w2,
                                             float* __restrict__ scale) {
    __shared__ float m[64];
    __shared__ float hid[8];
    int nl = blockIdx.x;
    int t  = threadIdx.x;
    m[t] = sums[nl * 64 + t] * (1.f / 1024.f);
    __syncthreads();
    if (t < 8) {
        float s = 0.f;
        #pragma unroll
        for (int ci = 0; ci < 64; ++ci) s += w1[t * 64 + ci] * m[ci];
        hid[t] = fmaxf(s, 0.f);
    }
    __syncthreads();
    float v = 0.f;
    #pragma unroll
    for (int r = 0; r < 8; ++r) v += w2[t * 8 + r] * hid[r];
    scale[nl * 64 + t] = 1.f + 1.f / (1.f + __expf(-v));
}

// ---------------------------------------------------------------------------
// K4: att = pr * scale, then the reshape bit-permutation + 4x4 tile assembly
// (windows don't overlap: cnt == 1). Coalesced writes, gathered reads.
__global__ __launch_bounds__(256) void k4_unscramble(const float* __restrict__ pr,
                                                     const float* __restrict__ scale,
                                                     float* __restrict__ oasm) {
    int tid = blockIdx.x * 256 + threadIdx.x;  // 16,777,216 = n*64c*128*128
    int W_ = tid & 127;
    int H_ = (tid >> 7) & 127;
    int c  = (tid >> 14) & 63;
    int n  = tid >> 20;
    int i = H_ >> 5, h2 = H_ & 31;
    int j = W_ >> 5, w2 = W_ & 31;
    int l  = c >> 2;
    int l2 = i * 4 + j;
    int cc = (c & 3) * 16 + (h2 >> 1);
    int hh = (h2 & 1) * 16 + (w2 >> 1);
    int ww = (w2 & 1) * 16 + l2;
    int nl = n * 16 + l;
    oasm[tid] = pr[(size_t)nl * 65536 + cc * PK + hh * 32 + ww] * scale[nl * 64 + cc];
}

// ---------------------------------------------------------------------------
// K5: conv3 (1x1, concat[out, x2] 128 -> 64 ch) + bias. Tile 64co x 64px, K=128.
__global__ __launch_bounds__(256) void k5_conv3(const float* __restrict__ oasm,
                                                const float* __restrict__ x2,
                                                const float* __restrict__ w3,
                                                const float* __restrict__ b3,
                                                float* __restrict__ out) {
    __shared__ __align__(16) float lx[64 * 64];
    int bid = blockIdx.x;
    int n   = bid >> 8;
    int p0  = (bid & 255) << 6;
    int t   = threadIdx.x;
    int cog = t & 15, pxg = t >> 4;
    int co0 = cog * 4, px0 = pxg * 4;
    float acc[4][4];
    #pragma unroll
    for (int c = 0; c < 4; ++c) {
        float b = b3[co0 + c];
        #pragma unroll
        for (int p = 0; p < 4; ++p) acc[c][p] = b;
    }
    for (int phase = 0; phase < 2; ++phase) {
        const float* src = (phase == 0 ? oasm : x2) + (size_t)n * 64 * P + p0;
        __syncthreads();
        #pragma unroll
        for (int k = 0; k < 4; ++k) {
            int u = t + k * 256;
            int ci = u >> 4, px4 = u & 15;
            *(float4*)(lx + ci * 64 + px4 * 4) = *(const float4*)(src + ci * P + px4 * 4);
        }
        __syncthreads();
        for (int cb = 0; cb < 16; ++cb) {
            float4 w4[4];
            #pragma unroll
            for (int c = 0; c < 4; ++c)
                w4[c] = *(const float4*)(w3 + (co0 + c) * 128 + phase * 64 + cb * 4);
            #pragma unroll
            for (int q = 0; q < 4; ++q) {
                float4 xv = *(const float4*)(lx + (cb * 4 + q) * 64 + px0);
                const float* xp = (const float*)&xv;
                #pragma unroll
                for (int c = 0; c < 4; ++c) {
                    float wv = ((const float*)&w4[c])[q];
                    #pragma unroll
                    for (int p = 0; p < 4; ++p) acc[c][p] += wv * xp[p];
                }
            }
        }
    }
    #pragma unroll
    for (int c = 0; c < 4; ++c) {
        *(float4*)(out + ((size_t)n * 64 + co0 + c) * P + p0 + px0) =
            make_float4(acc[c][0], acc[c][1], acc[c][2], acc[c][3]);
    }
}

// ---------------------------------------------------------------------------
extern "C" void kernel_launch(void* const* d_in, const int* in_sizes, int n_in,
                              void* d_out, int out_size, void* d_ws, size_t ws_size,
                              hipStream_t stream) {
    const float* x       = (const float*)d_in[0];
    const float* conv1_w = (const float*)d_in[1];
    const float* conv1_b = (const float*)d_in[2];
    const float* conv2_w = (const float*)d_in[3];
    const float* conv2_b = (const float*)d_in[4];
    const float* conv3_w = (const float*)d_in[5];
    const float* conv3_b = (const float*)d_in[6];
    const float* pos_w   = (const float*)d_in[7];
    const float* pos_b   = (const float*)d_in[8];
    const float* se_w1   = (const float*)d_in[9];
    const float* se_w2   = (const float*)d_in[10];

    float* ws     = (float*)d_ws;
    float* x1     = ws + OFF_X1;
    float* x2     = ws + OFF_X2;
    float* pooled = ws + OFF_POOL;
    float* sums   = ws + OFF_SUMS;
    float* scale  = ws + OFF_SCALE;
    float* wmod   = ws + OFF_WMOD;
    float* pr     = x1;      // x1 dead after K2
    float* oasm   = pooled;  // pooled dead after K3

    k0_prep      <<<208,   256, 0, stream>>>(pos_w, conv2_w, wmod, sums);
    k1_conv1     <<<4096,  256, 0, stream>>>(x, conv1_w, conv1_b, x1, x2);
    k2_pool      <<<65536, 256, 0, stream>>>(x1, pooled);
    k3_pr        <<<4096,  256, 0, stream>>>(pooled, wmod, conv2_b, pos_b, pr, sums);
    k3b_se       <<<256,   64,  0, stream>>>(sums, se_w1, se_w2, scale);
    k4_unscramble<<<65536, 256, 0, stream>>>(pr, scale, oasm);
    k5_conv3     <<<4096,  256, 0, stream>>>(oasm, x2, conv3_w, conv3_b, (float*)d_out);
}

// Round 2
// 620.027 us; speedup vs baseline: 1.3266x; 1.3266x over previous
//
#include <hip/hip_runtime.h>

// Problem constants
constexpr int N = 16, C = 64, H = 128, W = 128, P = H * W;   // P = 16384
constexpr int NL = 256, PK = 1024;                            // 256 windows, 32x32 each

// Workspace layout (float units)
constexpr size_t OFF_X1T   = 0;         // bf16 [n][16384px][64c] = 8.4M floats; later oasm (16.8M, spans X1T+POOL)
constexpr size_t OFF_POOL  = 8388608;   // bf16 [nl][1024px][64c] = 8.4M floats
constexpr size_t OFF_X2    = 16777216;  // fp32 [n][64c][16384px]
constexpr size_t OFF_PR    = 33554432;  // fp32 [nl][64co][1024px]
constexpr size_t OFF_SUMS  = 50331648;  // 16384 fp32
constexpr size_t OFF_SCALE = OFF_SUMS + 16384;   // 16384 fp32
constexpr size_t OFF_WLAY  = OFF_SCALE + 16384;  // bf16 [9tap][2cib][64co][32ci] = 36864 ushort

typedef short bf16x8 __attribute__((ext_vector_type(8)));
typedef float f32x4  __attribute__((ext_vector_type(4)));

__device__ inline unsigned short f2bf(float f) {
    unsigned u = __float_as_uint(f);
    unsigned r = (u + 0x7FFFu + ((u >> 16) & 1u)) >> 16;
    return (unsigned short)r;
}
__device__ inline float bf2f(unsigned short h) {
    return __uint_as_float(((unsigned)h) << 16);
}

// ---------------------------------------------------------------------------
// K0: merge conv2 (1x1) into center tap of pos_w; emit bf16 A-fragment layout
//     wlay[tap][cib][co][ci32]; zero SE sums. 208*256 = 53248 = 36864+16384.
__global__ __launch_bounds__(256) void k0_prep(const float* __restrict__ pos_w,
                                               const float* __restrict__ conv2_w,
                                               unsigned short* __restrict__ wlay,
                                               float* __restrict__ sums) {
    int t = blockIdx.x * 256 + threadIdx.x;
    if (t < 36864) {
        int cir = t & 31;
        int co  = (t >> 5) & 63;
        int cib = (t >> 11) & 1;
        int tap = t >> 12;                 // 0..8
        int ci  = cib * 32 + cir;
        float v = pos_w[(co * 64 + ci) * 9 + tap];
        if (tap == 4) v += conv2_w[co * 64 + ci];
        wlay[t] = f2bf(v);
    } else {
        sums[t - 36864] = 0.f;
    }
}

// ---------------------------------------------------------------------------
// K1: conv1 (1x1, 64 -> 128 ch) + bias. Tile: 128co x 64px, K=64.
// Writes x1 half as bf16 channel-minor [n][px][64c]; x2 half fp32 as before.
__global__ __launch_bounds__(256) void k1_conv1(const float* __restrict__ x,
                                                const float* __restrict__ w1,
                                                const float* __restrict__ b1,
                                                unsigned short* __restrict__ x1t,
                                                float* __restrict__ x2) {
    __shared__ __align__(16) float lx[64 * 64];
    int bid = blockIdx.x;
    int n   = bid >> 8;
    int p0  = (bid & 255) << 6;
    const float* xg = x + (size_t)n * C * P + p0;
    int t = threadIdx.x;
    #pragma unroll
    for (int k = 0; k < 4; ++k) {
        int u = t + k * 256;
        int ci = u >> 4, px4 = u & 15;
        *(float4*)(lx + ci * 64 + px4 * 4) = *(const float4*)(xg + ci * P + px4 * 4);
    }
    __syncthreads();
    int cog = t & 31, pxg = t >> 5;
    int co0 = cog * 4, px0 = pxg * 8;
    float acc[4][8];
    #pragma unroll
    for (int c = 0; c < 4; ++c) {
        float b = b1[co0 + c];
        #pragma unroll
        for (int p = 0; p < 8; ++p) acc[c][p] = b;
    }
    for (int cb = 0; cb < 16; ++cb) {
        float4 w4[4];
        #pragma unroll
        for (int c = 0; c < 4; ++c)
            w4[c] = *(const float4*)(w1 + (co0 + c) * 64 + cb * 4);
        float4 xv[4][2];
        #pragma unroll
        for (int q = 0; q < 4; ++q) {
            xv[q][0] = *(const float4*)(lx + (cb * 4 + q) * 64 + px0);
            xv[q][1] = *(const float4*)(lx + (cb * 4 + q) * 64 + px0 + 4);
        }
        #pragma unroll
        for (int q = 0; q < 4; ++q) {
            const float* xa = (const float*)&xv[q][0];
            const float* xb = (const float*)&xv[q][1];
            #pragma unroll
            for (int c = 0; c < 4; ++c) {
                float wv = ((const float*)&w4[c])[q];
                #pragma unroll
                for (int p = 0; p < 4; ++p) {
                    acc[c][p]     += wv * xa[p];
                    acc[c][p + 4] += wv * xb[p];
                }
            }
        }
    }
    if (cog < 16) {
        // x1 half -> bf16 [n][px][co], 8B per px per thread (half-wave coalesced)
        #pragma unroll
        for (int p = 0; p < 8; ++p) {
            ushort4 w = make_ushort4(f2bf(acc[0][p]), f2bf(acc[1][p]),
                                     f2bf(acc[2][p]), f2bf(acc[3][p]));
            *(ushort4*)(x1t + ((size_t)n * P + p0 + px0 + p) * 64 + co0) = w;
        }
    } else {
        #pragma unroll
        for (int c = 0; c < 4; ++c) {
            float* dst = x2 + ((size_t)n * 64 + (co0 - 64 + c)) * P + p0 + px0;
            *(float4*)dst       = make_float4(acc[c][0], acc[c][1], acc[c][2], acc[c][3]);
            *(float4*)(dst + 4) = make_float4(acc[c][4], acc[c][5], acc[c][6], acc[c][7]);
        }
    }
}

// ---------------------------------------------------------------------------
// K2: adaptive pool 34->32 == clamped 2x2 avg. bf16 in, bf16 out, channel-minor.
__global__ __launch_bounds__(256) void k2_pool(const unsigned short* __restrict__ x1t,
                                               unsigned short* __restrict__ pooledT) {
    int tid = blockIdx.x * 256 + threadIdx.x;  // 16,777,216 = 256nl * 1024px * 64c
    int c   = tid & 63;
    int opx = (tid >> 6) & 1023;
    int nl  = tid >> 16;
    int n = nl >> 4, l = nl & 15;
    int i = l >> 2, j = l & 3;
    int ow = opx & 31, oh = opx >> 5;
    int sh = oh + (oh >> 4);
    int sw = ow + (ow >> 4);
    int u = i * 34 + sh - 4;
    int v = j * 34 + sw - 4;
    int r0 = min(max(u, 0), 127), r1 = min(max(u + 1, 0), 127);
    int c0 = min(max(v, 0), 127), c1 = min(max(v + 1, 0), 127);
    const unsigned short* src = x1t + (size_t)n * P * 64 + c;
    float s = bf2f(src[(r0 * 128 + c0) * 64]) + bf2f(src[(r0 * 128 + c1) * 64]) +
              bf2f(src[(r1 * 128 + c0) * 64]) + bf2f(src[(r1 * 128 + c1) * 64]);
    pooledT[tid] = f2bf(0.25f * s);
}

// ---------------------------------------------------------------------------
// K3: pr = 3x3 SAME conv (conv2 folded into center tap) + biases, via bf16 MFMA.
// Block: one window nl, 8 pr-rows. 4 waves; each wave: 2 rows x 32 cols, all 64 co.
// LDS: 10 rows x 34 cols x 64ci bf16, pixel stride padded to 72 (144 B, 9x16B
// => conflict-free ds_read_b128 B-fragments). K = 9 taps x 2 x 32ci.
__global__ __launch_bounds__(256) void k3_pr_mfma(const unsigned short* __restrict__ pooledT,
                                                  const unsigned short* __restrict__ wlay,
                                                  const float* __restrict__ b2,
                                                  const float* __restrict__ posb,
                                                  float* __restrict__ pr,
                                                  float* __restrict__ sums) {
    __shared__ __align__(16) unsigned short lxs[340 * 72];  // 48960 B
    int bid = blockIdx.x;
    int nl  = bid >> 2;
    int r0  = (bid & 3) * 8;
    int t   = threadIdx.x;
    const unsigned short* psrc = pooledT + (size_t)nl * 65536;
    #pragma unroll
    for (int it = 0; it < 11; ++it) {
        int e = t + it * 256;                 // 2720 chunks = 340px * 8 * 16B
        if (e < 2720) {
            int pix = e >> 3, part = e & 7;
            int lr  = pix / 34;               // 0..9
            int lc  = pix - lr * 34;          // 0..33
            int gr  = r0 - 1 + lr;
            int gc  = lc - 1;
            uint4 v = make_uint4(0, 0, 0, 0);
            if ((unsigned)gr < 32u && (unsigned)gc < 32u)
                v = *(const uint4*)(psrc + ((size_t)(gr * 32 + gc)) * 64 + part * 8);
            *(uint4*)(lxs + pix * 72 + part * 8) = v;
        }
    }
    __syncthreads();
    int wave = t >> 6, lane = t & 63;
    int quad = lane >> 4, l16 = lane & 15;
    int wrow0 = wave * 2;
    f32x4 acc[4][4] = {};                     // [co-tile][px-tile]
    #pragma unroll
    for (int tap = 0; tap < 9; ++tap) {
        int dh = tap / 3, dw = tap % 3;
        #pragma unroll
        for (int cib = 0; cib < 2; ++cib) {
            bf16x8 af[4], bfr[4];
            #pragma unroll
            for (int ct = 0; ct < 4; ++ct)
                af[ct] = *(const bf16x8*)(wlay + (((tap * 2 + cib) * 64) + ct * 16 + l16) * 32 + quad * 8);
            #pragma unroll
            for (int pt = 0; pt < 4; ++pt) {
                int pix = (wrow0 + (pt >> 1) + dh) * 34 + ((pt & 1) * 16 + l16 + dw);
                bfr[pt] = *(const bf16x8*)(lxs + pix * 72 + cib * 32 + quad * 8);
            }
            #pragma unroll
            for (int ct = 0; ct < 4; ++ct)
                #pragma unroll
                for (int pt = 0; pt < 4; ++pt)
                    acc[ct][pt] = __builtin_amdgcn_mfma_f32_16x16x32_bf16(af[ct], bfr[pt], acc[ct][pt], 0, 0, 0);
        }
    }
    // epilogue: bias, pr write, SE partial sums
    #pragma unroll
    for (int ct = 0; ct < 4; ++ct) {
        #pragma unroll
        for (int r = 0; r < 4; ++r) {
            int co = ct * 16 + quad * 4 + r;
            float bias = b2[co] + posb[co];
            float s = 0.f;
            #pragma unroll
            for (int pt = 0; pt < 4; ++pt) {
                float v = acc[ct][pt][r] + bias;
                int row = r0 + wrow0 + (pt >> 1);
                int col = (pt & 1) * 16 + l16;
                pr[(size_t)nl * 65536 + co * 1024 + row * 32 + col] = v;
                s += v;
            }
            s += __shfl_xor(s, 1);
            s += __shfl_xor(s, 2);
            s += __shfl_xor(s, 4);
            s += __shfl_xor(s, 8);
            if (l16 == 0) atomicAdd(&sums[nl * 64 + co], s);
        }
    }
}

// ---------------------------------------------------------------------------
// K3b: SE per window: mean -> 64->8 relu -> 8->64 sigmoid; scale = 1 + s.
__global__ __launch_bounds__(64) void k3b_se(const float* __restrict__ sums,
                                             const float* __restrict__ w1,
                                             const float* __restrict__ w2,
                                             float* __restrict__ scale) {
    __shared__ float m[64];
    __shared__ float hid[8];
    int nl = blockIdx.x;
    int t  = threadIdx.x;
    m[t] = sums[nl * 64 + t] * (1.f / 1024.f);
    __syncthreads();
    if (t < 8) {
        float s = 0.f;
        #pragma unroll
        for (int ci = 0; ci < 64; ++ci) s += w1[t * 64 + ci] * m[ci];
        hid[t] = fmaxf(s, 0.f);
    }
    __syncthreads();
    float v = 0.f;
    #pragma unroll
    for (int r = 0; r < 8; ++r) v += w2[t * 8 + r] * hid[r];
    scale[nl * 64 + t] = 1.f + 1.f / (1.f + __expf(-v));
}

// ---------------------------------------------------------------------------
// K4: att = pr * scale + reshape bit-permutation + 4x4 tile assembly.
__global__ __launch_bounds__(256) void k4_unscramble(const float* __restrict__ pr,
                                                     const float* __restrict__ scale,
                                                     float* __restrict__ oasm) {
    int tid = blockIdx.x * 256 + threadIdx.x;  // 16,777,216 = n*64c*128*128
    int W_ = tid & 127;
    int H_ = (tid >> 7) & 127;
    int c  = (tid >> 14) & 63;
    int n  = tid >> 20;
    int i = H_ >> 5, h2 = H_ & 31;
    int j = W_ >> 5, w2 = W_ & 31;
    int l  = c >> 2;
    int l2 = i * 4 + j;
    int cc = (c & 3) * 16 + (h2 >> 1);
    int hh = (h2 & 1) * 16 + (w2 >> 1);
    int ww = (w2 & 1) * 16 + l2;
    int nl = n * 16 + l;
    oasm[tid] = pr[(size_t)nl * 65536 + cc * PK + hh * 32 + ww] * scale[nl * 64 + cc];
}

// ---------------------------------------------------------------------------
// K5: conv3 (1x1, concat[out, x2] 128 -> 64 ch) + bias. Tile 64co x 64px, K=128.
__global__ __launch_bounds__(256) void k5_conv3(const float* __restrict__ oasm,
                                                const float* __restrict__ x2,
                                                const float* __restrict__ w3,
                                                const float* __restrict__ b3,
                                                float* __restrict__ out) {
    __shared__ __align__(16) float lx[64 * 64];
    int bid = blockIdx.x;
    int n   = bid >> 8;
    int p0  = (bid & 255) << 6;
    int t   = threadIdx.x;
    int cog = t & 15, pxg = t >> 4;
    int co0 = cog * 4, px0 = pxg * 4;
    float acc[4][4];
    #pragma unroll
    for (int c = 0; c < 4; ++c) {
        float b = b3[co0 + c];
        #pragma unroll
        for (int p = 0; p < 4; ++p) acc[c][p] = b;
    }
    for (int phase = 0; phase < 2; ++phase) {
        const float* src = (phase == 0 ? oasm : x2) + (size_t)n * 64 * P + p0;
        __syncthreads();
        #pragma unroll
        for (int k = 0; k < 4; ++k) {
            int u = t + k * 256;
            int ci = u >> 4, px4 = u & 15;
            *(float4*)(lx + ci * 64 + px4 * 4) = *(const float4*)(src + ci * P + px4 * 4);
        }
        __syncthreads();
        for (int cb = 0; cb < 16; ++cb) {
            float4 w4[4];
            #pragma unroll
            for (int c = 0; c < 4; ++c)
                w4[c] = *(const float4*)(w3 + (co0 + c) * 128 + phase * 64 + cb * 4);
            #pragma unroll
            for (int q = 0; q < 4; ++q) {
                float4 xv = *(const float4*)(lx + (cb * 4 + q) * 64 + px0);
                const float* xp = (const float*)&xv;
                #pragma unroll
                for (int c = 0; c < 4; ++c) {
                    float wv = ((const float*)&w4[c])[q];
                    #pragma unroll
                    for (int p = 0; p < 4; ++p) acc[c][p] += wv * xp[p];
                }
            }
        }
    }
    #pragma unroll
    for (int c = 0; c < 4; ++c) {
        *(float4*)(out + ((size_t)n * 64 + co0 + c) * P + p0 + px0) =
            make_float4(acc[c][0], acc[c][1], acc[c][2], acc[c][3]);
    }
}

// ---------------------------------------------------------------------------
extern "C" void kernel_launch(void* const* d_in, const int* in_sizes, int n_in,
                              void* d_out, int out_size, void* d_ws, size_t ws_size,
                              hipStream_t stream) {
    const float* x       = (const float*)d_in[0];
    const float* conv1_w = (const float*)d_in[1];
    const float* conv1_b = (const float*)d_in[2];
    const float* conv2_w = (const float*)d_in[3];
    const float* conv2_b = (const float*)d_in[4];
    const float* conv3_w = (const float*)d_in[5];
    const float* conv3_b = (const float*)d_in[6];
    const float* pos_w   = (const float*)d_in[7];
    const float* pos_b   = (const float*)d_in[8];
    const float* se_w1   = (const float*)d_in[9];
    const float* se_w2   = (const float*)d_in[10];

    float* ws = (float*)d_ws;
    unsigned short* x1t     = (unsigned short*)(ws + OFF_X1T);
    unsigned short* pooledT = (unsigned short*)(ws + OFF_POOL);
    float* x2    = ws + OFF_X2;
    float* pr    = ws + OFF_PR;
    float* sums  = ws + OFF_SUMS;
    float* scale = ws + OFF_SCALE;
    unsigned short* wlay = (unsigned short*)(ws + OFF_WLAY);
    float* oasm  = ws + OFF_X1T;   // reuses x1t+pooledT region (both dead after k3)

    k0_prep      <<<208,   256, 0, stream>>>(pos_w, conv2_w, wlay, sums);
    k1_conv1     <<<4096,  256, 0, stream>>>(x, conv1_w, conv1_b, x1t, x2);
    k2_pool      <<<65536, 256, 0, stream>>>(x1t, pooledT);
    k3_pr_mfma   <<<1024,  256, 0, stream>>>(pooledT, wlay, conv2_b, pos_b, pr, sums);
    k3b_se       <<<256,   64,  0, stream>>>(sums, se_w1, se_w2, scale);
    k4_unscramble<<<65536, 256, 0, stream>>>(pr, scale, oasm);
    k5_conv3     <<<4096,  256, 0, stream>>>(oasm, x2, conv3_w, conv3_b, (float*)d_out);
}

// Round 3
// 308.011 us; speedup vs baseline: 2.6705x; 2.0130x over previous
//
#include <hip/hip_runtime.h>

// Problem constants
constexpr int N = 16, C = 64, H = 128, W = 128, P = H * W;   // P = 16384
constexpr int NL = 256, PK = 1024;                            // 256 windows, 32x32 each

// Workspace layout (float units). Regions alias across kernel lifetimes:
//   RA: xT   (k_tr -> k1), then pooledT (k2 -> k3)        8,388,608 fl
//   RB: x1t  (k1 -> k2),   then pr bf16 (k3 -> k4)        8,388,608 fl
//   RC: xcat (k1/k4 -> k5)                               16,777,216 fl
constexpr size_t OFF_RA    = 0;
constexpr size_t OFF_RB    = 8388608;
constexpr size_t OFF_RC    = 16777216;
constexpr size_t OFF_SUMS  = 33554432;           // 16384 fp32
constexpr size_t OFF_SCALE = OFF_SUMS  + 16384;  // 16384 fp32
constexpr size_t OFF_WMOD  = OFF_SCALE + 16384;  // 36864 ush = 18432 fl
constexpr size_t OFF_W1L   = OFF_WMOD  + 18432;  // 8192 ush = 4096 fl
constexpr size_t OFF_W3L   = OFF_W1L   + 4096;   // 8192 ush = 4096 fl

typedef short bf16x8 __attribute__((ext_vector_type(8)));
typedef float f32x4  __attribute__((ext_vector_type(4)));

__device__ inline unsigned short f2bf(float f) {
    unsigned u = __float_as_uint(f);
    unsigned r = (u + 0x7FFFu + ((u >> 16) & 1u)) >> 16;
    return (unsigned short)r;
}
__device__ inline float bf2f(unsigned short h) {
    return __uint_as_float(((unsigned)h) << 16);
}

// ---------------------------------------------------------------------------
// K0: weight prep. wmod[tap][cib][64co][32ci] (conv2 merged into center tap),
//     w1lay[cib(2)][128co][32ci], w3lay[cib(4)][64co][32ci]; zero SE sums.
//     272*256 = 69632 = 36864 + 8192 + 8192 + 16384.
__global__ __launch_bounds__(256) void k0_prep(const float* __restrict__ pos_w,
                                               const float* __restrict__ conv2_w,
                                               const float* __restrict__ w1,
                                               const float* __restrict__ w3,
                                               unsigned short* __restrict__ wmod,
                                               unsigned short* __restrict__ w1lay,
                                               unsigned short* __restrict__ w3lay,
                                               float* __restrict__ sums) {
    int t = blockIdx.x * 256 + threadIdx.x;
    if (t < 36864) {
        int cir = t & 31;
        int co  = (t >> 5) & 63;
        int cib = (t >> 11) & 1;
        int tap = t >> 12;
        int ci  = cib * 32 + cir;
        float v = pos_w[(co * 64 + ci) * 9 + tap];
        if (tap == 4) v += conv2_w[co * 64 + ci];
        wmod[t] = f2bf(v);
    } else if (t < 45056) {
        int u = t - 36864;                 // w1lay: [cib(2)][co(128)][ci32]
        int cir = u & 31;
        int co  = (u >> 5) & 127;
        int cib = u >> 12;
        w1lay[u] = f2bf(w1[co * 64 + cib * 32 + cir]);
    } else if (t < 53248) {
        int u = t - 45056;                 // w3lay: [cib(4)][co(64)][ci32]
        int cir = u & 31;
        int co  = (u >> 5) & 63;
        int cib = u >> 11;
        w3lay[u] = f2bf(w3[co * 128 + cib * 32 + cir]);
    } else {
        sums[t - 53248] = 0.f;
    }
}

// ---------------------------------------------------------------------------
// K_TR: x fp32 [n][64ci][16384px] -> xT bf16 channel-minor [n][px][64ci].
// LDS-tiled transpose, 64ci x 64px per block, +65 pad (2-way = free).
__global__ __launch_bounds__(256) void k_tr(const float* __restrict__ x,
                                            unsigned short* __restrict__ xT) {
    __shared__ float lds[64 * 65];
    int bid = blockIdx.x;
    int n   = bid >> 8;
    int px0 = (bid & 255) << 6;
    const float* src = x + (size_t)n * 64 * P + px0;
    int t = threadIdx.x;
    #pragma unroll
    for (int k = 0; k < 4; ++k) {
        int u = t + k * 256;
        int ci = u >> 4, px4 = u & 15;
        float4 v = *(const float4*)(src + (size_t)ci * P + px4 * 4);
        float* d = lds + ci * 65 + px4 * 4;
        d[0] = v.x; d[1] = v.y; d[2] = v.z; d[3] = v.w;
    }
    __syncthreads();
    int cig = t & 15, pxl = t >> 4;
    #pragma unroll
    for (int k = 0; k < 4; ++k) {
        int px = pxl + k * 16;
        ushort4 o;
        o.x = f2bf(lds[(cig * 4 + 0) * 65 + px]);
        o.y = f2bf(lds[(cig * 4 + 1) * 65 + px]);
        o.z = f2bf(lds[(cig * 4 + 2) * 65 + px]);
        o.w = f2bf(lds[(cig * 4 + 3) * 65 + px]);
        *(ushort4*)(xT + ((size_t)n * P + px0 + px) * 64 + cig * 4) = o;
    }
}

// ---------------------------------------------------------------------------
// K1: conv1 (1x1, 64 -> 128 ch) + bias via bf16 MFMA. Block: 128 px, 128 co.
// Writes x1t bf16 [n][px][64] (co<64) and xcat[n][px][128] ch 64..127 (co>=64).
__global__ __launch_bounds__(256) void k1_conv1(const unsigned short* __restrict__ xT,
                                                const unsigned short* __restrict__ w1lay,
                                                const float* __restrict__ b1,
                                                unsigned short* __restrict__ x1t,
                                                unsigned short* __restrict__ xcat) {
    __shared__ __align__(16) unsigned short lxs[128 * 72];  // 18 KB
    int bid = blockIdx.x;
    int n   = bid >> 7;
    int px0 = (bid & 127) << 7;
    const unsigned short* src = xT + ((size_t)n * P + px0) * 64;
    int t = threadIdx.x;
    #pragma unroll
    for (int it = 0; it < 4; ++it) {
        int e = t + it * 256;              // 1024 chunks of 16 B
        int pix = e >> 3, part = e & 7;
        *(uint4*)(lxs + pix * 72 + part * 8) = *(const uint4*)(src + pix * 64 + part * 8);
    }
    __syncthreads();
    int wave = t >> 6, lane = t & 63;
    int quad = lane >> 4, l16 = lane & 15;
    int pxw = wave * 32;
    f32x4 acc[8][2] = {};
    #pragma unroll
    for (int cib = 0; cib < 2; ++cib) {
        bf16x8 af[8], bfr[2];
        #pragma unroll
        for (int ct = 0; ct < 8; ++ct)
            af[ct] = *(const bf16x8*)(w1lay + ((size_t)(cib * 128 + ct * 16 + l16)) * 32 + quad * 8);
        #pragma unroll
        for (int pt = 0; pt < 2; ++pt)
            bfr[pt] = *(const bf16x8*)(lxs + (pxw + pt * 16 + l16) * 72 + cib * 32 + quad * 8);
        #pragma unroll
        for (int ct = 0; ct < 8; ++ct)
            #pragma unroll
            for (int pt = 0; pt < 2; ++pt)
                acc[ct][pt] = __builtin_amdgcn_mfma_f32_16x16x32_bf16(af[ct], bfr[pt], acc[ct][pt], 0, 0, 0);
    }
    #pragma unroll
    for (int ct = 0; ct < 8; ++ct) {
        int co0 = ct * 16 + quad * 4;
        float4 bb = *(const float4*)(b1 + co0);
        #pragma unroll
        for (int pt = 0; pt < 2; ++pt) {
            int px = px0 + pxw + pt * 16 + l16;
            ushort4 o;
            o.x = f2bf(acc[ct][pt][0] + bb.x);
            o.y = f2bf(acc[ct][pt][1] + bb.y);
            o.z = f2bf(acc[ct][pt][2] + bb.z);
            o.w = f2bf(acc[ct][pt][3] + bb.w);
            if (co0 < 64)
                *(ushort4*)(x1t + ((size_t)n * P + px) * 64 + co0) = o;
            else
                *(ushort4*)(xcat + ((size_t)n * P + px) * 128 + co0) = o;
        }
    }
}

// ---------------------------------------------------------------------------
// K2: adaptive pool 34->32 == clamped 2x2 avg. bf16 channel-minor in/out.
__global__ __launch_bounds__(256) void k2_pool(const unsigned short* __restrict__ x1t,
                                               unsigned short* __restrict__ pooledT) {
    int tid = blockIdx.x * 256 + threadIdx.x;  // 16,777,216 = 256nl * 1024px * 64c
    int c   = tid & 63;
    int opx = (tid >> 6) & 1023;
    int nl  = tid >> 16;
    int n = nl >> 4, l = nl & 15;
    int i = l >> 2, j = l & 3;
    int ow = opx & 31, oh = opx >> 5;
    int sh = oh + (oh >> 4);
    int sw = ow + (ow >> 4);
    int u = i * 34 + sh - 4;
    int v = j * 34 + sw - 4;
    int r0 = min(max(u, 0), 127), r1 = min(max(u + 1, 0), 127);
    int c0 = min(max(v, 0), 127), c1 = min(max(v + 1, 0), 127);
    const unsigned short* src = x1t + (size_t)n * P * 64 + c;
    float s = bf2f(src[(r0 * 128 + c0) * 64]) + bf2f(src[(r0 * 128 + c1) * 64]) +
              bf2f(src[(r1 * 128 + c0) * 64]) + bf2f(src[(r1 * 128 + c1) * 64]);
    pooledT[tid] = f2bf(0.25f * s);
}

// ---------------------------------------------------------------------------
// K3: pr = 3x3 SAME conv (conv2 folded) + biases via bf16 MFMA.
// Block: one window, 8 pr-rows; 4 waves x (2 rows x 32 cols x 64 co).
// pr written as bf16 [nl][64co][1024px]; SE partial sums via shfl + atomic.
__global__ __launch_bounds__(256) void k3_pr_mfma(const unsigned short* __restrict__ pooledT,
                                                  const unsigned short* __restrict__ wmod,
                                                  const float* __restrict__ b2,
                                                  const float* __restrict__ posb,
                                                  unsigned short* __restrict__ prb,
                                                  float* __restrict__ sums) {
    __shared__ __align__(16) unsigned short lxs[340 * 72];  // 48960 B
    int bid = blockIdx.x;
    int nl  = bid >> 2;
    int r0  = (bid & 3) * 8;
    int t   = threadIdx.x;
    const unsigned short* psrc = pooledT + (size_t)nl * 65536;
    #pragma unroll
    for (int it = 0; it < 11; ++it) {
        int e = t + it * 256;                 // 2720 chunks = 340px * 8 * 16B
        if (e < 2720) {
            int pix = e >> 3, part = e & 7;
            int lr  = pix / 34;
            int lc  = pix - lr * 34;
            int gr  = r0 - 1 + lr;
            int gc  = lc - 1;
            uint4 v = make_uint4(0, 0, 0, 0);
            if ((unsigned)gr < 32u && (unsigned)gc < 32u)
                v = *(const uint4*)(psrc + ((size_t)(gr * 32 + gc)) * 64 + part * 8);
            *(uint4*)(lxs + pix * 72 + part * 8) = v;
        }
    }
    __syncthreads();
    int wave = t >> 6, lane = t & 63;
    int quad = lane >> 4, l16 = lane & 15;
    int wrow0 = wave * 2;
    f32x4 acc[4][4] = {};
    #pragma unroll
    for (int tap = 0; tap < 9; ++tap) {
        int dh = tap / 3, dw = tap % 3;
        #pragma unroll
        for (int cib = 0; cib < 2; ++cib) {
            bf16x8 af[4], bfr[4];
            #pragma unroll
            for (int ct = 0; ct < 4; ++ct)
                af[ct] = *(const bf16x8*)(wmod + (((tap * 2 + cib) * 64) + ct * 16 + l16) * 32 + quad * 8);
            #pragma unroll
            for (int pt = 0; pt < 4; ++pt) {
                int pix = (wrow0 + (pt >> 1) + dh) * 34 + ((pt & 1) * 16 + l16 + dw);
                bfr[pt] = *(const bf16x8*)(lxs + pix * 72 + cib * 32 + quad * 8);
            }
            #pragma unroll
            for (int ct = 0; ct < 4; ++ct)
                #pragma unroll
                for (int pt = 0; pt < 4; ++pt)
                    acc[ct][pt] = __builtin_amdgcn_mfma_f32_16x16x32_bf16(af[ct], bfr[pt], acc[ct][pt], 0, 0, 0);
        }
    }
    #pragma unroll
    for (int ct = 0; ct < 4; ++ct) {
        #pragma unroll
        for (int r = 0; r < 4; ++r) {
            int co = ct * 16 + quad * 4 + r;
            float bias = b2[co] + posb[co];
            float s = 0.f;
            #pragma unroll
            for (int pt = 0; pt < 4; ++pt) {
                float v = acc[ct][pt][r] + bias;
                int row = r0 + wrow0 + (pt >> 1);
                int col = (pt & 1) * 16 + l16;
                prb[(size_t)nl * 65536 + co * 1024 + row * 32 + col] = f2bf(v);
                s += v;
            }
            s += __shfl_xor(s, 1);
            s += __shfl_xor(s, 2);
            s += __shfl_xor(s, 4);
            s += __shfl_xor(s, 8);
            if (l16 == 0) atomicAdd(&sums[nl * 64 + co], s);
        }
    }
}

// ---------------------------------------------------------------------------
// K3b: SE per window: mean -> 64->8 relu -> 8->64 sigmoid; scale = 1 + s.
__global__ __launch_bounds__(64) void k3b_se(const float* __restrict__ sums,
                                             const float* __restrict__ w1,
                                             const float* __restrict__ w2,
                                             float* __restrict__ scale) {
    __shared__ float m[64];
    __shared__ float hid[8];
    int nl = blockIdx.x;
    int t  = threadIdx.x;
    m[t] = sums[nl * 64 + t] * (1.f / 1024.f);
    __syncthreads();
    if (t < 8) {
        float s = 0.f;
        #pragma unroll
        for (int ci = 0; ci < 64; ++ci) s += w1[t * 64 + ci] * m[ci];
        hid[t] = fmaxf(s, 0.f);
    }
    __syncthreads();
    float v = 0.f;
    #pragma unroll
    for (int r = 0; r < 8; ++r) v += w2[t * 8 + r] * hid[r];
    scale[nl * 64 + t] = 1.f + 1.f / (1.f + __expf(-v));
}

// ---------------------------------------------------------------------------
// K4: att = pr * scale, bit-permutation unscramble, write att half of xcat
// (bf16 channel-minor, coalesced 16 B stores; gathers hit L2/L3-resident pr).
__global__ __launch_bounds__(256) void k4_unscramble(const unsigned short* __restrict__ prb,
                                                     const float* __restrict__ scale,
                                                     unsigned short* __restrict__ xcat) {
    int tid = blockIdx.x * 256 + threadIdx.x;  // 2,097,152 = 16n * 16384px * 8cg
    int cg = tid & 7;
    int W_ = (tid >> 3) & 127;
    int H_ = (tid >> 10) & 127;
    int n  = tid >> 17;
    int i = H_ >> 5, h2 = H_ & 31;
    int j = W_ >> 5, w2 = W_ & 31;
    int l2 = i * 4 + j;
    int hh = (h2 & 1) * 16 + (w2 >> 1);
    int ww = (w2 & 1) * 16 + l2;
    int pix = hh * 32 + ww;
    unsigned short o[8];
    #pragma unroll
    for (int m = 0; m < 8; ++m) {
        int c  = cg * 8 + m;
        int nl = n * 16 + (c >> 2);
        int cc = (c & 3) * 16 + (h2 >> 1);
        float v = bf2f(prb[(size_t)nl * 65536 + cc * 1024 + pix]) * scale[nl * 64 + cc];
        o[m] = f2bf(v);
    }
    *(uint4*)(xcat + ((size_t)n * P + H_ * 128 + W_) * 128 + cg * 8) = *(uint4*)o;
}

// ---------------------------------------------------------------------------
// K5: conv3 (1x1, 128 -> 64 ch) + bias via bf16 MFMA over xcat. Block: 128 px.
__global__ __launch_bounds__(256) void k5_conv3(const unsigned short* __restrict__ xcat,
                                                const unsigned short* __restrict__ w3lay,
                                                const float* __restrict__ b3,
                                                float* __restrict__ out) {
    __shared__ __align__(16) unsigned short lxs[128 * 136];  // 34 KB
    int bid = blockIdx.x;
    int n   = bid >> 7;
    int px0 = (bid & 127) << 7;
    const unsigned short* src = xcat + ((size_t)n * P + px0) * 128;
    int t = threadIdx.x;
    #pragma unroll
    for (int it = 0; it < 8; ++it) {
        int e = t + it * 256;              // 2048 chunks of 16 B
        int pix = e >> 4, part = e & 15;
        *(uint4*)(lxs + pix * 136 + part * 8) = *(const uint4*)(src + pix * 128 + part * 8);
    }
    __syncthreads();
    int wave = t >> 6, lane = t & 63;
    int quad = lane >> 4, l16 = lane & 15;
    int pxw = wave * 32;
    f32x4 acc[4][2] = {};
    #pragma unroll
    for (int cib = 0; cib < 4; ++cib) {
        bf16x8 af[4], bfr[2];
        #pragma unroll
        for (int ct = 0; ct < 4; ++ct)
            af[ct] = *(const bf16x8*)(w3lay + ((size_t)(cib * 64 + ct * 16 + l16)) * 32 + quad * 8);
        #pragma unroll
        for (int pt = 0; pt < 2; ++pt)
            bfr[pt] = *(const bf16x8*)(lxs + (pxw + pt * 16 + l16) * 136 + cib * 32 + quad * 8);
        #pragma unroll
        for (int ct = 0; ct < 4; ++ct)
            #pragma unroll
            for (int pt = 0; pt < 2; ++pt)
                acc[ct][pt] = __builtin_amdgcn_mfma_f32_16x16x32_bf16(af[ct], bfr[pt], acc[ct][pt], 0, 0, 0);
    }
    #pragma unroll
    for (int ct = 0; ct < 4; ++ct) {
        int co0 = ct * 16 + quad * 4;
        float4 bb = *(const float4*)(b3 + co0);
        #pragma unroll
        for (int pt = 0; pt < 2; ++pt) {
            int px = px0 + pxw + pt * 16 + l16;
            const float* bp = (const float*)&bb;
            #pragma unroll
            for (int r = 0; r < 4; ++r)
                out[((size_t)n * 64 + co0 + r) * P + px] = acc[ct][pt][r] + bp[r];
        }
    }
}

// ---------------------------------------------------------------------------
extern "C" void kernel_launch(void* const* d_in, const int* in_sizes, int n_in,
                              void* d_out, int out_size, void* d_ws, size_t ws_size,
                              hipStream_t stream) {
    const float* x       = (const float*)d_in[0];
    const float* conv1_w = (const float*)d_in[1];
    const float* conv1_b = (const float*)d_in[2];
    const float* conv2_w = (const float*)d_in[3];
    const float* conv2_b = (const float*)d_in[4];
    const float* conv3_w = (const float*)d_in[5];
    const float* conv3_b = (const float*)d_in[6];
    const float* pos_w   = (const float*)d_in[7];
    const float* pos_b   = (const float*)d_in[8];
    const float* se_w1   = (const float*)d_in[9];
    const float* se_w2   = (const float*)d_in[10];

    float* ws = (float*)d_ws;
    unsigned short* xT      = (unsigned short*)(ws + OFF_RA);
    unsigned short* pooledT = (unsigned short*)(ws + OFF_RA);  // after k1
    unsigned short* x1t     = (unsigned short*)(ws + OFF_RB);
    unsigned short* prb     = (unsigned short*)(ws + OFF_RB);  // after k2
    unsigned short* xcat    = (unsigned short*)(ws + OFF_RC);
    float* sums  = ws + OFF_SUMS;
    float* scale = ws + OFF_SCALE;
    unsigned short* wmod  = (unsigned short*)(ws + OFF_WMOD);
    unsigned short* w1lay = (unsigned short*)(ws + OFF_W1L);
    unsigned short* w3lay = (unsigned short*)(ws + OFF_W3L);

    k0_prep      <<<272,   256, 0, stream>>>(pos_w, conv2_w, conv1_w, conv3_w,
                                             wmod, w1lay, w3lay, sums);
    k_tr         <<<4096,  256, 0, stream>>>(x, xT);
    k1_conv1     <<<2048,  256, 0, stream>>>(xT, w1lay, conv1_b, x1t, xcat);
    k2_pool      <<<65536, 256, 0, stream>>>(x1t, pooledT);
    k3_pr_mfma   <<<1024,  256, 0, stream>>>(pooledT, wmod, conv2_b, pos_b, prb, sums);
    k3b_se       <<<256,   64,  0, stream>>>(sums, se_w1, se_w2, scale);
    k4_unscramble<<<8192,  256, 0, stream>>>(prb, scale, xcat);
    k5_conv3     <<<2048,  256, 0, stream>>>(xcat, w3lay, conv3_b, (float*)d_out);
}

// Round 4
// 257.942 us; speedup vs baseline: 3.1889x; 1.1941x over previous
//
#include <hip/hip_runtime.h>

// Problem constants
constexpr int N = 16, C = 64, H = 128, W = 128, P = H * W;   // P = 16384
constexpr int NL = 256, PK = 1024;                            // 256 windows, 32x32 each

// Workspace layout (float units). Liveness:
//   RA: prb bf16 [nl][64cc][1024px]   (k3 -> k4)           8,388,608 fl
//   RB: x1t bf16 [n][px][64c]         (k1 -> k3)           8,388,608 fl
//   RC: xcat bf16 [n][px][128c]       (k1 upper, k4 lower -> k5)  16,777,216 fl
constexpr size_t OFF_RA    = 0;
constexpr size_t OFF_RB    = 8388608;
constexpr size_t OFF_RC    = 16777216;
constexpr size_t OFF_SUMS  = 33554432;           // 16384 fp32
constexpr size_t OFF_SCALE = OFF_SUMS  + 16384;  // 16384 fp32
constexpr size_t OFF_WMOD  = OFF_SCALE + 16384;  // 36864 ush = 18432 fl
constexpr size_t OFF_W1L   = OFF_WMOD  + 18432;  // 8192 ush = 4096 fl
constexpr size_t OFF_W3L   = OFF_W1L   + 4096;   // 8192 ush = 4096 fl

typedef short bf16x8 __attribute__((ext_vector_type(8)));
typedef float f32x4  __attribute__((ext_vector_type(4)));

__device__ inline unsigned short f2bf(float f) {
    unsigned u = __float_as_uint(f);
    unsigned r = (u + 0x7FFFu + ((u >> 16) & 1u)) >> 16;
    return (unsigned short)r;
}
__device__ inline float bf2f(unsigned short h) {
    return __uint_as_float(((unsigned)h) << 16);
}

// ---------------------------------------------------------------------------
// K0: weight prep. wmod[tap][cib][64co][32ci] (conv2 merged into center tap),
//     w1lay[cib(2)][128co][32ci], w3lay[cib(4)][64co][32ci]; zero SE sums.
//     272*256 = 69632 = 36864 + 8192 + 8192 + 16384.
__global__ __launch_bounds__(256) void k0_prep(const float* __restrict__ pos_w,
                                               const float* __restrict__ conv2_w,
                                               const float* __restrict__ w1,
                                               const float* __restrict__ w3,
                                               unsigned short* __restrict__ wmod,
                                               unsigned short* __restrict__ w1lay,
                                               unsigned short* __restrict__ w3lay,
                                               float* __restrict__ sums) {
    int t = blockIdx.x * 256 + threadIdx.x;
    if (t < 36864) {
        int cir = t & 31;
        int co  = (t >> 5) & 63;
        int cib = (t >> 11) & 1;
        int tap = t >> 12;
        int ci  = cib * 32 + cir;
        float v = pos_w[(co * 64 + ci) * 9 + tap];
        if (tap == 4) v += conv2_w[co * 64 + ci];
        wmod[t] = f2bf(v);
    } else if (t < 45056) {
        int u = t - 36864;                 // w1lay: [cib(2)][co(128)][ci32]
        int cir = u & 31;
        int co  = (u >> 5) & 127;
        int cib = u >> 12;
        w1lay[u] = f2bf(w1[co * 64 + cib * 32 + cir]);
    } else if (t < 53248) {
        int u = t - 45056;                 // w3lay: [cib(4)][co(64)][ci32]
        int cir = u & 31;
        int co  = (u >> 5) & 63;
        int cib = u >> 11;
        w3lay[u] = f2bf(w3[co * 128 + cib * 32 + cir]);
    } else {
        sums[t - 53248] = 0.f;
    }
}

// ---------------------------------------------------------------------------
// K1: fused transpose + conv1 (1x1, 64->128) + bias via bf16 MFMA.
// Block: 128 px. Stage: fp32 LDS tile (64ci x 64px, +1 pad) -> bf16 LDS-B
// [128px][64ci] with 16B-chunk XOR swizzle (chunk' = chunk ^ (px&7)).
// Writes x1t bf16 [n][px][64] (co<64) and xcat[n][px][128] ch 64..127.
__global__ __launch_bounds__(256) void k1_conv1(const float* __restrict__ x,
                                                const unsigned short* __restrict__ w1lay,
                                                const float* __restrict__ b1,
                                                unsigned short* __restrict__ x1t,
                                                unsigned short* __restrict__ xcat) {
    __shared__ __align__(16) float lda[64 * 65];             // 16640 B
    __shared__ __align__(16) unsigned short ldb[128 * 64];   // 16384 B
    int bid = blockIdx.x;
    int n   = bid >> 7;
    int px0 = (bid & 127) << 7;
    int t   = threadIdx.x;
    #pragma unroll
    for (int s = 0; s < 2; ++s) {
        if (s) __syncthreads();
        const float* src = x + (size_t)n * 64 * P + px0 + s * 64;
        #pragma unroll
        for (int k = 0; k < 4; ++k) {
            int u = t + k * 256;            // 1024 float4 units = 64ci x 16px4
            int ci = u >> 4, px4 = u & 15;
            float4 v = *(const float4*)(src + (size_t)ci * P + px4 * 4);
            float* d = lda + ci * 65 + px4 * 4;
            d[0] = v.x; d[1] = v.y; d[2] = v.z; d[3] = v.w;
        }
        __syncthreads();
        int cig = t & 15, pxl = t >> 4;
        #pragma unroll
        for (int k = 0; k < 4; ++k) {
            int px = pxl + k * 16;          // 0..63 within sub-tile
            ushort4 o;
            o.x = f2bf(lda[(cig * 4 + 0) * 65 + px]);
            o.y = f2bf(lda[(cig * 4 + 1) * 65 + px]);
            o.z = f2bf(lda[(cig * 4 + 2) * 65 + px]);
            o.w = f2bf(lda[(cig * 4 + 3) * 65 + px]);
            int pg = s * 64 + px;
            int chunk = cig >> 1;
            *(ushort4*)(ldb + pg * 64 + ((chunk ^ (pg & 7)) * 8) + (cig & 1) * 4) = o;
        }
    }
    __syncthreads();
    int wave = t >> 6, lane = t & 63;
    int quad = lane >> 4, l16 = lane & 15;
    int pxw = wave * 32;
    f32x4 acc[8][2] = {};
    #pragma unroll
    for (int cib = 0; cib < 2; ++cib) {
        bf16x8 af[8], bfr[2];
        #pragma unroll
        for (int ct = 0; ct < 8; ++ct)
            af[ct] = *(const bf16x8*)(w1lay + ((size_t)(cib * 128 + ct * 16 + l16)) * 32 + quad * 8);
        #pragma unroll
        for (int pt = 0; pt < 2; ++pt) {
            int pg = pxw + pt * 16 + l16;
            int chunk = cib * 4 + quad;
            bfr[pt] = *(const bf16x8*)(ldb + pg * 64 + ((chunk ^ (pg & 7)) * 8));
        }
        #pragma unroll
        for (int ct = 0; ct < 8; ++ct)
            #pragma unroll
            for (int pt = 0; pt < 2; ++pt)
                acc[ct][pt] = __builtin_amdgcn_mfma_f32_16x16x32_bf16(af[ct], bfr[pt], acc[ct][pt], 0, 0, 0);
    }
    #pragma unroll
    for (int ct = 0; ct < 8; ++ct) {
        int co0 = ct * 16 + quad * 4;
        float4 bb = *(const float4*)(b1 + co0);
        #pragma unroll
        for (int pt = 0; pt < 2; ++pt) {
            int px = px0 + pxw + pt * 16 + l16;
            ushort4 o;
            o.x = f2bf(acc[ct][pt][0] + bb.x);
            o.y = f2bf(acc[ct][pt][1] + bb.y);
            o.z = f2bf(acc[ct][pt][2] + bb.z);
            o.w = f2bf(acc[ct][pt][3] + bb.w);
            if (co0 < 64)
                *(ushort4*)(x1t + ((size_t)n * P + px) * 64 + co0) = o;
            else
                *(ushort4*)(xcat + ((size_t)n * P + px) * 128 + co0) = o;
        }
    }
}

// ---------------------------------------------------------------------------
// K3: fused adaptive-pool + 3x3 SAME conv (conv2 folded) + biases via MFMA.
// Block: one window, 8 pr-rows. Staging is 2 phases of 32 ci; pooled values
// (clamped 2x2 avg of x1t) computed inline. LDS 340px x 32ush, XOR-swizzled
// (chunk' = chunk ^ ((pix>>1)&3)) => conflict-free b128, 21.8 KB => 4 blk/CU.
__global__ __launch_bounds__(256) void k3_pool_pr(const unsigned short* __restrict__ x1t,
                                                  const unsigned short* __restrict__ wmod,
                                                  const float* __restrict__ b2,
                                                  const float* __restrict__ posb,
                                                  unsigned short* __restrict__ prb,
                                                  float* __restrict__ sums) {
    __shared__ __align__(16) unsigned short lxs[340 * 32];  // 21760 B
    int bid = blockIdx.x;
    int nl  = bid >> 2;
    int r0  = (bid & 3) * 8;
    int n   = nl >> 4, wl = nl & 15;
    int wi  = wl >> 2, wj = wl & 3;
    int t   = threadIdx.x;
    const unsigned short* xb = x1t + (size_t)n * P * 64;
    int wave = t >> 6, lane = t & 63;
    int quad = lane >> 4, l16 = lane & 15;
    int wrow0 = wave * 2;
    f32x4 acc[4][4] = {};
    #pragma unroll
    for (int cib = 0; cib < 2; ++cib) {
        if (cib) __syncthreads();
        // ---- stage phase cib: 1360 chunks = 340 px x 4 parts of 8 ush ----
        for (int it = 0; it < 6; ++it) {
            int e = t + it * 256;
            if (e < 1360) {
                int pix = e >> 2, part = e & 3;
                int lr = pix / 34, lc = pix - lr * 34;
                int gr = r0 - 1 + lr, gc = lc - 1;
                unsigned short oc[8];
                if ((unsigned)gr < 32u && (unsigned)gc < 32u) {
                    int sh = gr + (gr >> 4), sw = gc + (gc >> 4);
                    int u = wi * 34 + sh - 4, v = wj * 34 + sw - 4;
                    int ra = min(max(u, 0), 127), rb = min(max(u + 1, 0), 127);
                    int ca = min(max(v, 0), 127), cb = min(max(v + 1, 0), 127);
                    int off = cib * 32 + part * 8;
                    uint4 A = *(const uint4*)(xb + (size_t)(ra * 128 + ca) * 64 + off);
                    uint4 B = *(const uint4*)(xb + (size_t)(ra * 128 + cb) * 64 + off);
                    uint4 Cc = *(const uint4*)(xb + (size_t)(rb * 128 + ca) * 64 + off);
                    uint4 D = *(const uint4*)(xb + (size_t)(rb * 128 + cb) * 64 + off);
                    const unsigned short* a = (const unsigned short*)&A;
                    const unsigned short* b = (const unsigned short*)&B;
                    const unsigned short* c = (const unsigned short*)&Cc;
                    const unsigned short* d = (const unsigned short*)&D;
                    #pragma unroll
                    for (int q = 0; q < 8; ++q)
                        oc[q] = f2bf(0.25f * (bf2f(a[q]) + bf2f(b[q]) + bf2f(c[q]) + bf2f(d[q])));
                } else {
                    #pragma unroll
                    for (int q = 0; q < 8; ++q) oc[q] = 0;
                }
                *(uint4*)(lxs + pix * 32 + ((part ^ ((pix >> 1) & 3)) * 8)) = *(const uint4*)oc;
            }
        }
        __syncthreads();
        // ---- compute: 9 taps x 16 MFMA ----
        #pragma unroll
        for (int tap = 0; tap < 9; ++tap) {
            int dh = tap / 3, dw = tap % 3;
            bf16x8 af[4], bfr[4];
            #pragma unroll
            for (int ct = 0; ct < 4; ++ct)
                af[ct] = *(const bf16x8*)(wmod + (((tap * 2 + cib) * 64) + ct * 16 + l16) * 32 + quad * 8);
            #pragma unroll
            for (int pt = 0; pt < 4; ++pt) {
                int pix = (wrow0 + (pt >> 1) + dh) * 34 + ((pt & 1) * 16 + l16 + dw);
                bfr[pt] = *(const bf16x8*)(lxs + pix * 32 + ((quad ^ ((pix >> 1) & 3)) * 8));
            }
            #pragma unroll
            for (int ct = 0; ct < 4; ++ct)
                #pragma unroll
                for (int pt = 0; pt < 4; ++pt)
                    acc[ct][pt] = __builtin_amdgcn_mfma_f32_16x16x32_bf16(af[ct], bfr[pt], acc[ct][pt], 0, 0, 0);
        }
    }
    // epilogue: bias, prb write (bf16), SE partial sums
    #pragma unroll
    for (int ct = 0; ct < 4; ++ct) {
        #pragma unroll
        for (int r = 0; r < 4; ++r) {
            int co = ct * 16 + quad * 4 + r;
            float bias = b2[co] + posb[co];
            float s = 0.f;
            #pragma unroll
            for (int pt = 0; pt < 4; ++pt) {
                float v = acc[ct][pt][r] + bias;
                int row = r0 + wrow0 + (pt >> 1);
                int col = (pt & 1) * 16 + l16;
                prb[(size_t)nl * 65536 + co * 1024 + row * 32 + col] = f2bf(v);
                s += v;
            }
            s += __shfl_xor(s, 1);
            s += __shfl_xor(s, 2);
            s += __shfl_xor(s, 4);
            s += __shfl_xor(s, 8);
            if (l16 == 0) atomicAdd(&sums[nl * 64 + co], s);
        }
    }
}

// ---------------------------------------------------------------------------
// K3b: SE per window: mean -> 64->8 relu -> 8->64 sigmoid; scale = 1 + s.
__global__ __launch_bounds__(64) void k3b_se(const float* __restrict__ sums,
                                             const float* __restrict__ w1,
                                             const float* __restrict__ w2,
                                             float* __restrict__ scale) {
    __shared__ float m[64];
    __shared__ float hid[8];
    int nl = blockIdx.x;
    int t  = threadIdx.x;
    m[t] = sums[nl * 64 + t] * (1.f / 1024.f);
    __syncthreads();
    if (t < 8) {
        float s = 0.f;
        #pragma unroll
        for (int ci = 0; ci < 64; ++ci) s += w1[t * 64 + ci] * m[ci];
        hid[t] = fmaxf(s, 0.f);
    }
    __syncthreads();
    float v = 0.f;
    #pragma unroll
    for (int r = 0; r < 8; ++r) v += w2[t * 8 + r] * hid[r];
    scale[nl * 64 + t] = 1.f + 1.f / (1.f + __expf(-v));
}

// ---------------------------------------------------------------------------
// K4: att = pr * scale + bit-permutation unscramble, x4 vectorized: each
// thread = (n, i, h2, w2, cg); one ushort4 load covers j=0..3 outputs.
// Writes att half of xcat (coalesced 16 B stores).
__global__ __launch_bounds__(256) void k4_unscramble(const unsigned short* __restrict__ prb,
                                                     const float* __restrict__ scale,
                                                     unsigned short* __restrict__ xcat) {
    int tid = blockIdx.x * 256 + threadIdx.x;  // 524288 = 16n * 4i * 32h2 * 32w2 * 8cg
    int cg = tid & 7;
    int w2 = (tid >> 3) & 31;
    int h2 = (tid >> 8) & 31;
    int i  = (tid >> 13) & 3;
    int n  = tid >> 15;
    int hh = (h2 & 1) * 16 + (w2 >> 1);
    int pixbase = hh * 32 + (w2 & 1) * 16 + i * 4;   // + j, j=0..3
    unsigned short o[4][8];
    #pragma unroll
    for (int m = 0; m < 8; ++m) {
        int c  = cg * 8 + m;
        int nl = n * 16 + (c >> 2);
        int cc = (c & 3) * 16 + (h2 >> 1);
        ushort4 v = *(const ushort4*)(prb + (size_t)nl * 65536 + cc * 1024 + pixbase);
        float s = scale[nl * 64 + cc];
        o[0][m] = f2bf(bf2f(v.x) * s);
        o[1][m] = f2bf(bf2f(v.y) * s);
        o[2][m] = f2bf(bf2f(v.z) * s);
        o[3][m] = f2bf(bf2f(v.w) * s);
    }
    int H_ = i * 32 + h2;
    #pragma unroll
    for (int j = 0; j < 4; ++j) {
        int W_ = j * 32 + w2;
        *(uint4*)(xcat + ((size_t)n * P + H_ * 128 + W_) * 128 + cg * 8) = *(const uint4*)o[j];
    }
}

// ---------------------------------------------------------------------------
// K5: conv3 (1x1, 128 -> 64 ch) + bias via bf16 MFMA over xcat. Block: 128 px.
__global__ __launch_bounds__(256) void k5_conv3(const unsigned short* __restrict__ xcat,
                                                const unsigned short* __restrict__ w3lay,
                                                const float* __restrict__ b3,
                                                float* __restrict__ out) {
    __shared__ __align__(16) unsigned short lxs[128 * 136];  // 34816 B
    int bid = blockIdx.x;
    int n   = bid >> 7;
    int px0 = (bid & 127) << 7;
    const unsigned short* src = xcat + ((size_t)n * P + px0) * 128;
    int t = threadIdx.x;
    #pragma unroll
    for (int it = 0; it < 8; ++it) {
        int e = t + it * 256;              // 2048 chunks of 16 B
        int pix = e >> 4, part = e & 15;
        *(uint4*)(lxs + pix * 136 + part * 8) = *(const uint4*)(src + pix * 128 + part * 8);
    }
    __syncthreads();
    int wave = t >> 6, lane = t & 63;
    int quad = lane >> 4, l16 = lane & 15;
    int pxw = wave * 32;
    f32x4 acc[4][2] = {};
    #pragma unroll
    for (int cib = 0; cib < 4; ++cib) {
        bf16x8 af[4], bfr[2];
        #pragma unroll
        for (int ct = 0; ct < 4; ++ct)
            af[ct] = *(const bf16x8*)(w3lay + ((size_t)(cib * 64 + ct * 16 + l16)) * 32 + quad * 8);
        #pragma unroll
        for (int pt = 0; pt < 2; ++pt)
            bfr[pt] = *(const bf16x8*)(lxs + (pxw + pt * 16 + l16) * 136 + cib * 32 + quad * 8);
        #pragma unroll
        for (int ct = 0; ct < 4; ++ct)
            #pragma unroll
            for (int pt = 0; pt < 2; ++pt)
                acc[ct][pt] = __builtin_amdgcn_mfma_f32_16x16x32_bf16(af[ct], bfr[pt], acc[ct][pt], 0, 0, 0);
    }
    #pragma unroll
    for (int ct = 0; ct < 4; ++ct) {
        int co0 = ct * 16 + quad * 4;
        float4 bb = *(const float4*)(b3 + co0);
        #pragma unroll
        for (int pt = 0; pt < 2; ++pt) {
            int px = px0 + pxw + pt * 16 + l16;
            const float* bp = (const float*)&bb;
            #pragma unroll
            for (int r = 0; r < 4; ++r)
                out[((size_t)n * 64 + co0 + r) * P + px] = acc[ct][pt][r] + bp[r];
        }
    }
}

// ---------------------------------------------------------------------------
extern "C" void kernel_launch(void* const* d_in, const int* in_sizes, int n_in,
                              void* d_out, int out_size, void* d_ws, size_t ws_size,
                              hipStream_t stream) {
    const float* x       = (const float*)d_in[0];
    const float* conv1_w = (const float*)d_in[1];
    const float* conv1_b = (const float*)d_in[2];
    const float* conv2_w = (const float*)d_in[3];
    const float* conv2_b = (const float*)d_in[4];
    const float* conv3_w = (const float*)d_in[5];
    const float* conv3_b = (const float*)d_in[6];
    const float* pos_w   = (const float*)d_in[7];
    const float* pos_b   = (const float*)d_in[8];
    const float* se_w1   = (const float*)d_in[9];
    const float* se_w2   = (const float*)d_in[10];

    float* ws = (float*)d_ws;
    unsigned short* prb  = (unsigned short*)(ws + OFF_RA);
    unsigned short* x1t  = (unsigned short*)(ws + OFF_RB);
    unsigned short* xcat = (unsigned short*)(ws + OFF_RC);
    float* sums  = ws + OFF_SUMS;
    float* scale = ws + OFF_SCALE;
    unsigned short* wmod  = (unsigned short*)(ws + OFF_WMOD);
    unsigned short* w1lay = (unsigned short*)(ws + OFF_W1L);
    unsigned short* w3lay = (unsigned short*)(ws + OFF_W3L);

    k0_prep      <<<272,  256, 0, stream>>>(pos_w, conv2_w, conv1_w, conv3_w,
                                            wmod, w1lay, w3lay, sums);
    k1_conv1     <<<2048, 256, 0, stream>>>(x, w1lay, conv1_b, x1t, xcat);
    k3_pool_pr   <<<1024, 256, 0, stream>>>(x1t, wmod, conv2_b, pos_b, prb, sums);
    k3b_se       <<<256,  64,  0, stream>>>(sums, se_w1, se_w2, scale);
    k4_unscramble<<<2048, 256, 0, stream>>>(prb, scale, xcat);
    k5_conv3     <<<2048, 256, 0, stream>>>(xcat, w3lay, conv3_b, (float*)d_out);
}